// Round 6
// baseline (217.722 us; speedup 1.0000x reference)
//
#include <hip/hip_runtime.h>
#include <math.h>

#define NQ 12
#define NL 4
#define NA 6
#define BATCH 4096
#define NT 256   // 4 waves; lane = t&63 (wires 0..5), wv = t>>6 (wires 6,7), 4 reg bits (wires 8..11 in P0)

typedef float f2 __attribute__((ext_vector_type(2)));

// HW-verified (R3-R5 end-to-end) packed complex primitives; state/coeff = (re,im) in a VGPR pair.
#define CMUL(d, u, a)  asm("v_pk_mul_f32 %0, %1, %2 op_sel_hi:[0,1]"                 : "=v"(d) : "v"(u), "v"(a))
#define CMACR(d, u, a) asm("v_pk_fma_f32 %0, %1, %2, %0 op_sel_hi:[0,1,1]"           : "+v"(d) : "v"(u), "v"(a))
#define CMACI(d, u, a) asm("v_pk_fma_f32 %0, %1, %2, %0 op_sel:[1,1,0] op_sel_hi:[1,0,1] neg_lo:[1,0,0]" : "+v"(d) : "v"(u), "v"(a))
#define WFENCE() asm volatile("s_waitcnt lgkmcnt(0)" ::: "memory")

#define BFLY(A0, A1, U00, U01, U10, U11) do { \
    f2 _a0 = (A0), _a1 = (A1), _n0, _n1; \
    CMUL (_n0, U00, _a0); CMACI(_n0, U00, _a0); \
    CMACR(_n0, U01, _a1); CMACI(_n0, U01, _a1); \
    CMUL (_n1, U10, _a0); CMACI(_n1, U10, _a0); \
    CMACR(_n1, U11, _a1); CMACI(_n1, U11, _a1); \
    (A0) = _n0; (A1) = _n1; } while (0)

// Layouts (amp index i, 12 bits; lane 6b, wv 2b, j 4b):
//  P0: i = (lane<<6)|(wv<<4)|j
//      wires 0..5 = lane bits 5..0, wire6 = wv1, wire7 = wv0, wires 8..11 = j bits 3..0
//  P1: i = (j<<8)|((lane&3)<<6)|(wv<<4)|(lane>>2)
//      wires 0..3 = j bits 3..0, wire4 = lane bit1, wire5 = lane bit0,
//      wire6 = wv1, wire7 = wv0, wires 8..11 = lane bits 5..2
// Wave-local transpose P0<->P1 (involution): new st[j'] of lane L = old st[L>>2] of lane (j'<<2)|(L&3).
// Wires 4,5 identical in both layouts (lane bits 1,0) -> shuffle gates via xor-2 / xor-1.
// Wires 6,7 (wv bits) layout-invariant -> chunked LDS exchange (partners tix^128 / tix^64).
//
// NOTE R4/R5: 2-arg __launch_bounds__ made the allocator spill (R4: scratch; R5: AGPR moves).
// Single-arg bounds gave clean allocations in R2/R3 -> use single-arg.

__global__ __launch_bounds__(NT) void qdqn_kernel(
    const float* __restrict__ x,       // [BATCH,12]
    const float* __restrict__ weights, // [4,12,3]
    const float* __restrict__ fc_w,    // [6,12]
    const float* __restrict__ fc_b,    // [6]
    float* __restrict__ out)           // [BATCH,6]
{
    __shared__ __align__(16) float smemf[4608];   // 18432B: transpose (4 x 64x17 f32) UNION exchange (256 x 9 f2)
    __shared__ __align__(16) f2 rotc[NL * NQ][4]; // u00,u01,u10,u11 as (re,im)
    __shared__ float encc[NQ], encs[NQ];
    __shared__ float red[4][NQ];
    __shared__ float qout[NQ];

    const int tix  = threadIdx.x;
    const int lane = tix & 63;
    const int wv   = tix >> 6;
    const int wv1  = (wv >> 1) & 1;
    const int wv0  = wv & 1;
    const int b    = blockIdx.x;

    // --- setup: 48 rot matrices (threads 0..47), encoding sincos (threads 64..75) ---
    if (tix < NL * NQ) {
        float phi = weights[tix * 3 + 0];
        float th  = weights[tix * 3 + 1];
        float om  = weights[tix * 3 + 2];
        float sth, cth, sa, ca, sb, cb;
        sincosf(0.5f * th, &sth, &cth);
        sincosf(0.5f * (phi + om), &sa, &ca);
        sincosf(0.5f * (phi - om), &sb, &cb);
        rotc[tix][0] = (f2){ ca * cth, -sa * cth };  // u00
        rotc[tix][1] = (f2){ -cb * sth, -sb * sth }; // u01
        rotc[tix][2] = (f2){ cb * sth, -sb * sth };  // u10
        rotc[tix][3] = (f2){ ca * cth,  sa * cth };  // u11
    } else if (tix >= 64 && tix < 64 + NQ) {
        int q = tix - 64;
        float s, c;
        sincosf(0.5f * x[b * NQ + q], &s, &c);
        encc[q] = c; encs[q] = s;
    }
    __syncthreads();

    // --- RY product state in P0 ---
    f2 st[16];
    {
        float pre = 1.0f;
#pragma unroll
        for (int q = 0; q < 6; ++q)
            pre *= ((lane >> (5 - q)) & 1) ? encs[q] : encc[q];
        pre *= wv1 ? encs[6] : encc[6];
        pre *= wv0 ? encs[7] : encc[7];
        const float c8 = encc[8],  s8 = encs[8];
        const float c9 = encc[9],  s9 = encs[9];
        const float cA = encc[10], sA = encs[10];
        const float cB = encc[11], sB = encs[11];
#pragma unroll
        for (int j = 0; j < 16; ++j) {
            float v = pre;
            v *= (j & 8) ? s8 : c8;
            v *= (j & 4) ? s9 : c9;
            v *= (j & 2) ? sA : cA;
            v *= (j & 1) ? sB : cB;
            st[j] = (f2){ v, 0.0f };
        }
    }

    float* const tb  = smemf + wv * (64 * 17);   // per-wave transpose buffer
    f2*    const xb  = (f2*)smemf;               // exchange view (aliases all transpose buffers)
    const int prt7 = tix ^ 64;    // wire7 partner (wv0 flip)
    const int prt6 = tix ^ 128;   // wire6 partner (wv1 flip)

#pragma unroll 1
    for (int h = 0; h < 2; ++h) {
#pragma unroll
        for (int sub = 0; sub < 2; ++sub) {
            const int l  = 2 * h + sub;
            const int gb = l * NQ;
            const bool even = (sub == 0);   // even layer: enter P0, exit P1; odd: reverse

            // --- first reg-gate quartet (P0: wires 8..11) or (P1: wires 0..3) ---
#pragma unroll
            for (int bq = 0; bq < 4; ++bq) {
                const int wire = even ? (11 - bq) : (3 - bq);
                const f2 u00 = rotc[gb + wire][0], u01 = rotc[gb + wire][1];
                const f2 u10 = rotc[gb + wire][2], u11 = rotc[gb + wire][3];
                const int S = 1 << bq;
#pragma unroll
                for (int m = 0; m < 8; ++m) {
                    const int j0 = ((m & ~(S - 1)) << 1) | (m & (S - 1));
                    BFLY(st[j0], st[j0 + S], u00, u01, u10, u11);
                }
            }

            // --- wave-local 64x16 transpose (P0 <-> P1), component-wise, fence-only ---
            WFENCE();
#pragma unroll
            for (int j = 0; j < 16; ++j) tb[lane * 17 + j] = st[j].x;
            WFENCE();
#pragma unroll
            for (int j = 0; j < 16; ++j) st[j].x = tb[(((j << 2) | (lane & 3)) * 17) + (lane >> 2)];
            WFENCE();
#pragma unroll
            for (int j = 0; j < 16; ++j) tb[lane * 17 + j] = st[j].y;
            WFENCE();
#pragma unroll
            for (int j = 0; j < 16; ++j) st[j].y = tb[(((j << 2) | (lane & 3)) * 17) + (lane >> 2)];

            // --- second reg-gate quartet ---
#pragma unroll
            for (int bq = 0; bq < 4; ++bq) {
                const int wire = even ? (3 - bq) : (11 - bq);
                const f2 u00 = rotc[gb + wire][0], u01 = rotc[gb + wire][1];
                const f2 u10 = rotc[gb + wire][2], u11 = rotc[gb + wire][3];
                const int S = 1 << bq;
#pragma unroll
                for (int m = 0; m < 8; ++m) {
                    const int j0 = ((m & ~(S - 1)) << 1) | (m & (S - 1));
                    BFLY(st[j0], st[j0 + S], u00, u01, u10, u11);
                }
            }

            // --- shuffle gates: wire4 (lane bit1, xor 2), wire5 (lane bit0, xor 1) ---
#pragma unroll
            for (int sg = 0; sg < 2; ++sg) {
                const int wire = 4 + sg;
                const int mask = sg ? 1 : 2;
                const f2 u00 = rotc[gb + wire][0], u01 = rotc[gb + wire][1];
                const f2 u10 = rotc[gb + wire][2], u11 = rotc[gb + wire][3];
                const int bit = (lane >> (1 - sg)) & 1;
                const f2 ca = bit ? u11 : u00;
                const f2 cb = bit ? u10 : u01;
#pragma unroll
                for (int j = 0; j < 16; ++j) {
                    f2 as = st[j], ap, n;
                    ap.x = __shfl_xor(as.x, mask, 64);
                    ap.y = __shfl_xor(as.y, mask, 64);
                    CMUL(n, ca, as); CMACI(n, ca, as); CMACR(n, cb, ap); CMACI(n, cb, ap);
                    st[j] = n;
                }
            }

            // --- exchange gates: wire7 (partner tix^64), wire6 (partner tix^128) ---
#pragma unroll
            for (int eg = 0; eg < 2; ++eg) {
                const int wire = eg ? 6 : 7;
                const int prt  = eg ? prt6 : prt7;
                const int bit  = eg ? wv1 : wv0;
                const f2 u00 = rotc[gb + wire][0], u01 = rotc[gb + wire][1];
                const f2 u10 = rotc[gb + wire][2], u11 = rotc[gb + wire][3];
                const f2 ca = bit ? u11 : u00;
                const f2 cb = bit ? u10 : u01;
#pragma unroll
                for (int c = 0; c < 2; ++c) {
                    __syncthreads();
#pragma unroll
                    for (int k = 0; k < 8; ++k) xb[tix * 9 + k] = st[c * 8 + k];
                    __syncthreads();
#pragma unroll
                    for (int k = 0; k < 8; ++k) {
                        f2 as = st[c * 8 + k];
                        f2 ap = xb[prt * 9 + k];
                        f2 n;
                        CMUL(n, ca, as); CMACI(n, ca, as); CMACR(n, cb, ap); CMACI(n, cb, ap);
                        st[c * 8 + k] = n;
                    }
                }
                __syncthreads();
            }

            // --- CZ diagonal in current layout ---
            if (even) {
                // P1: pairs (l1&l0)+(l0&wv1)+(wv1&wv0)+(wv0&l5)+lane pairs(5,4)(4,3)(3,2); per-j: (j0&l1), j-pairs
                const int par = ((lane >> 1) & lane & 1) + ((lane & 1) & wv1) + (wv1 & wv0)
                              + (wv0 & ((lane >> 5) & 1)) + __popc(lane & (lane >> 1) & 0x1C);
                const float base = (par & 1) ? -1.0f : 1.0f;
                const float sOdd = (lane & 2) ? -base : base;   // extra (j&1)&(lane bit1) term
#pragma unroll
                for (int j = 0; j < 16; ++j) {
                    float s = (j & 1) ? sOdd : base;
                    if (__popc(j & (j >> 1)) & 1) s = -s;       // compile-time per j
                    st[j] *= s;
                }
            } else {
                // P0: pairs all-5-lane + (l0&wv1) + (wv1&wv0); per-j: (wv0 & j3), j-pairs
                const int par = __popc(lane & (lane >> 1)) + ((lane & 1) & wv1) + (wv1 & wv0);
                const float base = (par & 1) ? -1.0f : 1.0f;
                const float sHi = wv0 ? -base : base;           // extra (wv0 & (j&8)) term
#pragma unroll
                for (int j = 0; j < 16; ++j) {
                    float s = (j & 8) ? sHi : base;
                    if (__popc(j & (j >> 1)) & 1) s = -s;       // compile-time per j
                    st[j] *= s;
                }
            }
        }
    }

    // --- measurement in P0 ---
    float tot = 0.f, m8 = 0.f, m9 = 0.f, m10 = 0.f, m11 = 0.f;
#pragma unroll
    for (int j = 0; j < 16; ++j) {
        const float p = st[j].x * st[j].x + st[j].y * st[j].y;
        tot += p;
        m8  += (j & 8) ? -p : p;
        m9  += (j & 4) ? -p : p;
        m10 += (j & 2) ? -p : p;
        m11 += (j & 1) ? -p : p;
    }
    float part[NQ];
#pragma unroll
    for (int q = 0; q < 6; ++q)
        part[q] = ((lane >> (5 - q)) & 1) ? -tot : tot;
    part[6] = wv1 ? -tot : tot;
    part[7] = wv0 ? -tot : tot;
    part[8] = m8; part[9] = m9; part[10] = m10; part[11] = m11;

#pragma unroll
    for (int off = 32; off > 0; off >>= 1) {
#pragma unroll
        for (int q = 0; q < NQ; ++q)
            part[q] += __shfl_down(part[q], off, 64);
    }
    if (lane == 0) {
#pragma unroll
        for (int q = 0; q < NQ; ++q) red[wv][q] = part[q];
    }
    __syncthreads();
    if (tix < NQ) qout[tix] = red[0][tix] + red[1][tix] + red[2][tix] + red[3][tix];
    __syncthreads();

    if (tix < NA) {
        float acc = fc_b[tix];
#pragma unroll
        for (int q = 0; q < NQ; ++q)
            acc += qout[q] * fc_w[tix * NQ + q];
        out[b * NA + tix] = acc;
    }
}

extern "C" void kernel_launch(void* const* d_in, const int* in_sizes, int n_in,
                              void* d_out, int out_size, void* d_ws, size_t ws_size,
                              hipStream_t stream) {
    const float* x   = (const float*)d_in[0];
    const float* w   = (const float*)d_in[1];
    const float* fcw = (const float*)d_in[2];
    const float* fcb = (const float*)d_in[3];
    qdqn_kernel<<<BATCH, NT, 0, stream>>>(x, w, fcw, fcb, (float*)d_out);
}

// Round 8
// 200.053 us; speedup vs baseline: 1.0883x; 1.0883x over previous
//
#include <hip/hip_runtime.h>
#include <math.h>

#define NQ 12
#define NL 4
#define NA 6
#define BATCH 4096
#define NT 256
#define RSTR 17   // buf row stride in f2 units (136 B, 8B-aligned rows). b64 transpose ops land
                  // exactly on the 4-dword/bank wave64 floor both directions (R8 bank analysis).

typedef float f2 __attribute__((ext_vector_type(2)));

// HW-verified (R3-R6 end-to-end) packed complex primitives; state/coeff = (re,im) in a VGPR pair.
#define CMUL(d, u, a)  asm("v_pk_mul_f32 %0, %1, %2 op_sel_hi:[0,1]"                 : "=v"(d) : "v"(u), "v"(a))
#define CMACR(d, u, a) asm("v_pk_fma_f32 %0, %1, %2, %0 op_sel_hi:[0,1,1]"           : "+v"(d) : "v"(u), "v"(a))
#define CMACI(d, u, a) asm("v_pk_fma_f32 %0, %1, %2, %0 op_sel:[1,1,0] op_sel_hi:[1,0,1] neg_lo:[1,0,0]" : "+v"(d) : "v"(u), "v"(a))
#define WFENCE() asm volatile("s_waitcnt lgkmcnt(0)" ::: "memory")

#define BFLY(A0, A1, U00, U01, U10, U11) do { \
    f2 _a0 = (A0), _a1 = (A1), _n0, _n1; \
    CMUL (_n0, U00, _a0); CMACI(_n0, U00, _a0); \
    CMACR(_n0, U01, _a1); CMACI(_n0, U01, _a1); \
    CMUL (_n1, U10, _a0); CMACI(_n1, U10, _a0); \
    CMACR(_n1, U11, _a1); CMACI(_n1, U11, _a1); \
    (A0) = _n0; (A1) = _n1; } while (0)

// One 2x2 gate on reg bit bq; coeffs from global (wave-uniform -> scalar cache, zero DS ops).
#define GATE(gidx, bq) do { \
    const f2* _u = (const f2*)(rots + (gidx) * 8); \
    const f2 u00 = _u[0], u01 = _u[1], u10 = _u[2], u11 = _u[3]; \
    const int S = 1 << (bq); \
    _Pragma("unroll") \
    for (int m = 0; m < 8; ++m) { \
        const int j0 = ((m & ~(S - 1)) << 1) | (m & (S - 1)); \
        BFLY(st[j0], st[j0 + S], u00, u01, u10, u11); \
    } } while (0)

// Layouts (wire q <-> i-bit (11-q); lane lam 6b, wave w 2b, reg j 4b). R8: re-derived & spot-traced.
//  L1: i = (lam5,lam4,lam3,lam2,lam1,lam0, w1,w0, j3,j2,j1,j0)
//      wires 0..5 = lane, 6,7 = wave, 8..11 = reg(j3..j0)
//  L2: i = (lam5,lam4, j3,j2,j1,j0, w1,w0, lam3..lam0)
//      wires 2..5 = reg(j3..j0)
//  L3: i = (j3,j2, lam5,lam4, w1,w0, j1,j0, lam3..lam0)      [executed col_b=(lam5,lam4,w1,w0)]
//      wires 0,1 = reg(j3,j2), wires 6,7 = reg(j1,j0); wires 2,3 = lam5,lam4; 4,5 = w1,w0
// T_a (L1<->L2, INVOLUTION, wave-local): write row tix col j; read row (w<<6)|(lam&0x30)|j, col lam&0xF.
// T_b (L2<->L3, INVOLUTION, cross-wave): write row tix col j; read row ((j&3)<<6)|((j>>2)<<4)|(lam&0xF),
//      col ((lam>>4)<<2)|w.   [R7 bug: used a non-involutive "inverse" row formula on the way back]
// Verified: amp-trace thread(lam=5,w=2)st[9] <-> thread(37,1)st[2] both directions.

__global__ void rot_setup_kernel(const float* __restrict__ weights, float* __restrict__ ws) {
    const int g = threadIdx.x;
    if (g < NL * NQ) {
        const float phi = weights[g * 3 + 0];
        const float th  = weights[g * 3 + 1];
        const float om  = weights[g * 3 + 2];
        float sth, cth, sa, ca, sb, cb;
        sincosf(0.5f * th, &sth, &cth);
        sincosf(0.5f * (phi + om), &sa, &ca);
        sincosf(0.5f * (phi - om), &sb, &cb);
        float* o = ws + g * 8;
        o[0] =  ca * cth; o[1] = -sa * cth;   // u00
        o[2] = -cb * sth; o[3] = -sb * sth;   // u01
        o[4] =  cb * sth; o[5] = -sb * sth;   // u10
        o[6] =  ca * cth; o[7] =  sa * cth;   // u11
    }
}

__global__ __launch_bounds__(NT) void qdqn_kernel(
    const float* __restrict__ x,       // [BATCH,12]
    const float* __restrict__ rots,    // [48,8] from rot_setup_kernel (d_ws)
    const float* __restrict__ fc_w,    // [6,12]
    const float* __restrict__ fc_b,    // [6]
    float* __restrict__ out)           // [BATCH,6]
{
    __shared__ __align__(16) f2 buf[NT * RSTR];   // 34816 B state-transpose buffer
    __shared__ float encc[NQ], encs[NQ];
    __shared__ float red[4][NQ];
    __shared__ float qout[NQ];

    const int tix = threadIdx.x;
    const int lam = tix & 63;
    const int w   = tix >> 6;
    const int w1  = (w >> 1) & 1, w0 = w & 1;
    const int b   = blockIdx.x;

    if (tix < NQ) {
        float s, c;
        sincosf(0.5f * x[b * NQ + tix], &s, &c);
        encc[tix] = c; encs[tix] = s;
    }
    __syncthreads();

    // --- RY product state in L1 ---
    f2 st[16];
    {
        float pre = 1.0f;
#pragma unroll
        for (int q = 0; q < 6; ++q)
            pre *= ((lam >> (5 - q)) & 1) ? encs[q] : encc[q];
        pre *= w1 ? encs[6] : encc[6];
        pre *= w0 ? encs[7] : encc[7];
        const float c8 = encc[8],  s8 = encs[8];
        const float c9 = encc[9],  s9 = encs[9];
        const float cA = encc[10], sA = encs[10];
        const float cB = encc[11], sB = encs[11];
#pragma unroll
        for (int j = 0; j < 16; ++j) {
            float v = pre;
            v *= (j & 8) ? s8 : c8;
            v *= (j & 4) ? s9 : c9;
            v *= (j & 2) ? sA : cA;
            v *= (j & 1) ? sB : cB;
            st[j] = (f2){ v, 0.0f };
        }
    }

    const int col_b = ((lam >> 4) << 2) | w;   // T_b read column (both directions; involution)
    const int row_a = (w << 6) | (lam & 0x30); // T_a read row base
    const int col_a = lam & 0xF;

#pragma unroll 1
    for (int h = 0; h < 2; ++h) {
        // ================= forward layer l = 2h : L1 -> L2 -> L3 =================
        {
            const int gb = (2 * h) * NQ;
            GATE(gb + 11, 0); GATE(gb + 10, 1); GATE(gb + 9, 2); GATE(gb + 8, 3);
            // T_a (wave-local; prior readers of these rows were in-wave)
            WFENCE();
#pragma unroll
            for (int j = 0; j < 16; ++j) buf[tix * RSTR + j] = st[j];
            WFENCE();
#pragma unroll
            for (int j = 0; j < 16; ++j) st[j] = buf[(row_a | j) * RSTR + col_a];
            GATE(gb + 5, 0); GATE(gb + 4, 1); GATE(gb + 3, 2); GATE(gb + 2, 3);
            // T_b (cross-wave reads)
            WFENCE();
#pragma unroll
            for (int j = 0; j < 16; ++j) buf[tix * RSTR + j] = st[j];
            __syncthreads();
#pragma unroll
            for (int j = 0; j < 16; ++j)
                st[j] = buf[(((j & 3) << 6) | ((j >> 2) << 4) | (lam & 0xF)) * RSTR + col_b];
            GATE(gb + 7, 0); GATE(gb + 6, 1); GATE(gb + 1, 2); GATE(gb + 0, 3);
            // CZ in executed L3: i=(j3,j2,lam5,lam4,w1,w0,j1,j0,lam3..0)
            //   compile-time: (0,1)=j3&j2, (6,7)=j1&j0
            //   base: (2,3)=l5&l4, (3,4)=l4&w1, (4,5)=w1&w0, (8..11)=popc(lam&(lam>>1)&7)
            //   per-j: (1,2)=j2&l5 -> fA=l5 ; (5,6)=w0&j1 -> fB=w0 ; (7,8)=j0&l3 -> fC=l3
            {
                const int l5 = (lam >> 5) & 1, l4 = (lam >> 4) & 1, l3 = (lam >> 3) & 1;
                const int par = (l5 & l4) + (l4 & w1) + (w1 & w0) + __popc(lam & (lam >> 1) & 0x7);
                const float base = (par & 1) ? -1.0f : 1.0f;
                const float fA = l5 ? -1.0f : 1.0f;
                const float fB = w0 ? -1.0f : 1.0f;
                const float fC = l3 ? -1.0f : 1.0f;
#pragma unroll
                for (int j = 0; j < 16; ++j) {
                    float s = base;
                    if (j & 4) s *= fA;
                    if (j & 2) s *= fB;
                    if (j & 1) s *= fC;
                    if ((((j & 12) == 12) ? 1 : 0) ^ (((j & 3) == 3) ? 1 : 0)) s = -s; // compile-time
                    st[j] *= s;
                }
            }
        }
        // ================= reverse layer l = 2h+1 : L3 -> L2 -> L1 =================
        {
            const int gb = (2 * h + 1) * NQ;
            GATE(gb + 7, 0); GATE(gb + 6, 1); GATE(gb + 1, 2); GATE(gb + 0, 3);
            // T_b back (involution: SAME row/col formula; prior T_b reads were cross-wave)
            __syncthreads();
#pragma unroll
            for (int j = 0; j < 16; ++j) buf[tix * RSTR + j] = st[j];
            __syncthreads();
#pragma unroll
            for (int j = 0; j < 16; ++j)
                st[j] = buf[(((j & 3) << 6) | ((j >> 2) << 4) | (lam & 0xF)) * RSTR + col_b];
            GATE(gb + 5, 0); GATE(gb + 4, 1); GATE(gb + 3, 2); GATE(gb + 2, 3);
            // T_a back (prior T_b reads were cross-wave -> barrier before writes)
            __syncthreads();
#pragma unroll
            for (int j = 0; j < 16; ++j) buf[tix * RSTR + j] = st[j];
            WFENCE();
#pragma unroll
            for (int j = 0; j < 16; ++j) st[j] = buf[(row_a | j) * RSTR + col_a];
            GATE(gb + 11, 0); GATE(gb + 10, 1); GATE(gb + 9, 2); GATE(gb + 8, 3);
            // CZ in L1 (R6-verified formula)
            {
                const int par = __popc(lam & (lam >> 1)) + ((lam & 1) & w1) + (w1 & w0);
                const float base = (par & 1) ? -1.0f : 1.0f;
                const float sHi = w0 ? -base : base;   // (7,8) = w0 & j3
#pragma unroll
                for (int j = 0; j < 16; ++j) {
                    float s = (j & 8) ? sHi : base;
                    if (__popc(j & (j >> 1)) & 1) s = -s;  // compile-time per j
                    st[j] *= s;
                }
            }
        }
    }

    // --- measurement in L1 ---
    float tot = 0.f, m8 = 0.f, m9 = 0.f, m10 = 0.f, m11 = 0.f;
#pragma unroll
    for (int j = 0; j < 16; ++j) {
        const float p = st[j].x * st[j].x + st[j].y * st[j].y;
        tot += p;
        m8  += (j & 8) ? -p : p;
        m9  += (j & 4) ? -p : p;
        m10 += (j & 2) ? -p : p;
        m11 += (j & 1) ? -p : p;
    }
    float part[NQ];
#pragma unroll
    for (int q = 0; q < 6; ++q)
        part[q] = ((lam >> (5 - q)) & 1) ? -tot : tot;
    part[6] = w1 ? -tot : tot;
    part[7] = w0 ? -tot : tot;
    part[8] = m8; part[9] = m9; part[10] = m10; part[11] = m11;

#pragma unroll
    for (int off = 32; off > 0; off >>= 1) {
#pragma unroll
        for (int q = 0; q < NQ; ++q)
            part[q] += __shfl_down(part[q], off, 64);
    }
    if (lam == 0) {
#pragma unroll
        for (int q = 0; q < NQ; ++q) red[w][q] = part[q];
    }
    __syncthreads();
    if (tix < NQ) qout[tix] = red[0][tix] + red[1][tix] + red[2][tix] + red[3][tix];
    __syncthreads();

    if (tix < NA) {
        float acc = fc_b[tix];
#pragma unroll
        for (int q = 0; q < NQ; ++q)
            acc += qout[q] * fc_w[tix * NQ + q];
        out[b * NA + tix] = acc;
    }
}

extern "C" void kernel_launch(void* const* d_in, const int* in_sizes, int n_in,
                              void* d_out, int out_size, void* d_ws, size_t ws_size,
                              hipStream_t stream) {
    const float* x   = (const float*)d_in[0];
    const float* wts = (const float*)d_in[1];
    const float* fcw = (const float*)d_in[2];
    const float* fcb = (const float*)d_in[3];
    float* rots = (float*)d_ws;   // 48*8 f32 = 1536 B
    rot_setup_kernel<<<1, 64, 0, stream>>>(wts, rots);
    qdqn_kernel<<<BATCH, NT, 0, stream>>>(x, rots, fcw, fcb, (float*)d_out);
}

// Round 9
// 188.765 us; speedup vs baseline: 1.1534x; 1.0598x over previous
//
#include <hip/hip_runtime.h>
#include <math.h>

#define NQ 12
#define NL 4
#define NA 6
#define BATCH 4096
#define NT 256
#define RSTR 17   // f32 row stride; b32 transpose passes at stride 17 -> 2 lanes/bank (free, m136)

typedef float f2 __attribute__((ext_vector_type(2)));

// HW-verified (R3-R8 end-to-end) packed complex primitives; state/coeff = (re,im) in a VGPR pair.
#define CMUL(d, u, a)  asm("v_pk_mul_f32 %0, %1, %2 op_sel_hi:[0,1]"                 : "=v"(d) : "v"(u), "v"(a))
#define CMACR(d, u, a) asm("v_pk_fma_f32 %0, %1, %2, %0 op_sel_hi:[0,1,1]"           : "+v"(d) : "v"(u), "v"(a))
#define CMACI(d, u, a) asm("v_pk_fma_f32 %0, %1, %2, %0 op_sel:[1,1,0] op_sel_hi:[1,0,1] neg_lo:[1,0,0]" : "+v"(d) : "v"(u), "v"(a))
#define WFENCE() asm volatile("s_waitcnt lgkmcnt(0)" ::: "memory")

#define BFLY(A0, A1, U00, U01, U10, U11) do { \
    f2 _a0 = (A0), _a1 = (A1), _n0, _n1; \
    CMUL (_n0, U00, _a0); CMACI(_n0, U00, _a0); \
    CMACR(_n0, U01, _a1); CMACI(_n0, U01, _a1); \
    CMUL (_n1, U10, _a0); CMACI(_n1, U10, _a0); \
    CMACR(_n1, U11, _a1); CMACI(_n1, U11, _a1); \
    (A0) = _n0; (A1) = _n1; } while (0)

// One 2x2 gate on reg bit bq; coeffs from global (wave-uniform -> scalar cache, zero DS ops).
#define GATE(gidx, bq) do { \
    const f2* _u = (const f2*)(rots + (gidx) * 8); \
    const f2 u00 = _u[0], u01 = _u[1], u10 = _u[2], u11 = _u[3]; \
    const int S = 1 << (bq); \
    _Pragma("unroll") \
    for (int m = 0; m < 8; ++m) { \
        const int j0 = ((m & ~(S - 1)) << 1) | (m & (S - 1)); \
        BFLY(st[j0], st[j0 + S], u00, u01, u10, u11); \
    } } while (0)

// Layouts (wire q <-> i-bit (11-q); lane lam 6b, wave w 2b, reg j 4b). R8-verified end-to-end.
//  L1: i = (lam5..lam0, w1,w0, j3..j0)                wires 0..5 lane, 6,7 wave, 8..11 reg
//  L2: i = (lam5,lam4, j3..j0, w1,w0, lam3..lam0)     wires 2..5 reg
//  L3: i = (j3,j2, lam5,lam4, w1,w0, j1,j0, lam3..0)  wires 0,1,6,7 reg
// T_a (L1<->L2, involution, WAVE-LOCAL): write row tix col j; read row (w<<6)|(lam&0x30)|j, col lam&0xF.
// T_b (L2<->L3, involution, CROSS-WAVE): write row tix col j; read row ((j&3)<<6)|((j>>2)<<4)|(lam&0xF),
//      col ((lam>>4)<<2)|w.
// R9: transposes are two f32 component passes over a single 256x17 f32 buffer -> LDS 34.8->17.4 KB,
//     7 blocks/CU (VGPR-capped) vs 4. T_a fence-only; T_b needs internal barriers (cross-wave WAR).

__global__ void rot_setup_kernel(const float* __restrict__ weights, float* __restrict__ ws) {
    const int g = threadIdx.x;
    if (g < NL * NQ) {
        const float phi = weights[g * 3 + 0];
        const float th  = weights[g * 3 + 1];
        const float om  = weights[g * 3 + 2];
        float sth, cth, sa, ca, sb, cb;
        sincosf(0.5f * th, &sth, &cth);
        sincosf(0.5f * (phi + om), &sa, &ca);
        sincosf(0.5f * (phi - om), &sb, &cb);
        float* o = ws + g * 8;
        o[0] =  ca * cth; o[1] = -sa * cth;   // u00
        o[2] = -cb * sth; o[3] = -sb * sth;   // u01
        o[4] =  cb * sth; o[5] = -sb * sth;   // u10
        o[6] =  ca * cth; o[7] =  sa * cth;   // u11
    }
}

__global__ __launch_bounds__(NT) void qdqn_kernel(
    const float* __restrict__ x,       // [BATCH,12]
    const float* __restrict__ rots,    // [48,8] from rot_setup_kernel (d_ws)
    const float* __restrict__ fc_w,    // [6,12]
    const float* __restrict__ fc_b,    // [6]
    float* __restrict__ out)           // [BATCH,6]
{
    __shared__ __align__(16) float buf[NT * RSTR];   // 17408 B transpose buffer (f32 components)
    __shared__ float encc[NQ], encs[NQ];
    __shared__ float red[4][NQ];
    __shared__ float qout[NQ];

    const int tix = threadIdx.x;
    const int lam = tix & 63;
    const int w   = tix >> 6;
    const int w1  = (w >> 1) & 1, w0 = w & 1;
    const int b   = blockIdx.x;

    if (tix < NQ) {
        float s, c;
        sincosf(0.5f * x[b * NQ + tix], &s, &c);
        encc[tix] = c; encs[tix] = s;
    }
    __syncthreads();

    // --- RY product state in L1 ---
    f2 st[16];
    {
        float pre = 1.0f;
#pragma unroll
        for (int q = 0; q < 6; ++q)
            pre *= ((lam >> (5 - q)) & 1) ? encs[q] : encc[q];
        pre *= w1 ? encs[6] : encc[6];
        pre *= w0 ? encs[7] : encc[7];
        const float c8 = encc[8],  s8 = encs[8];
        const float c9 = encc[9],  s9 = encs[9];
        const float cA = encc[10], sA = encs[10];
        const float cB = encc[11], sB = encs[11];
#pragma unroll
        for (int j = 0; j < 16; ++j) {
            float v = pre;
            v *= (j & 8) ? s8 : c8;
            v *= (j & 4) ? s9 : c9;
            v *= (j & 2) ? sA : cA;
            v *= (j & 1) ? sB : cB;
            st[j] = (f2){ v, 0.0f };
        }
    }

    const int col_b = ((lam >> 4) << 2) | w;   // T_b read column (involution, both directions)
    const int row_a = (w << 6) | (lam & 0x30); // T_a read row base
    const int col_a = lam & 0xF;

    // T_a: wave-local, fence-only (all producers/consumers of touched rows in this wave)
#define TRANSPOSE_A() do { \
    WFENCE(); \
    _Pragma("unroll") for (int j = 0; j < 16; ++j) buf[tix * RSTR + j] = st[j].x; \
    WFENCE(); \
    _Pragma("unroll") for (int j = 0; j < 16; ++j) st[j].x = buf[(row_a | j) * RSTR + col_a]; \
    WFENCE(); \
    _Pragma("unroll") for (int j = 0; j < 16; ++j) buf[tix * RSTR + j] = st[j].y; \
    WFENCE(); \
    _Pragma("unroll") for (int j = 0; j < 16; ++j) st[j].y = buf[(row_a | j) * RSTR + col_a]; \
    } while (0)

    // T_b: cross-wave reads -> barriers between phases (caller provides the leading barrier/fence)
#define TRANSPOSE_B() do { \
    _Pragma("unroll") for (int j = 0; j < 16; ++j) buf[tix * RSTR + j] = st[j].x; \
    __syncthreads(); \
    _Pragma("unroll") for (int j = 0; j < 16; ++j) \
        st[j].x = buf[(((j & 3) << 6) | ((j >> 2) << 4) | (lam & 0xF)) * RSTR + col_b]; \
    __syncthreads(); \
    _Pragma("unroll") for (int j = 0; j < 16; ++j) buf[tix * RSTR + j] = st[j].y; \
    __syncthreads(); \
    _Pragma("unroll") for (int j = 0; j < 16; ++j) \
        st[j].y = buf[(((j & 3) << 6) | ((j >> 2) << 4) | (lam & 0xF)) * RSTR + col_b]; \
    } while (0)

#pragma unroll 1
    for (int h = 0; h < 2; ++h) {
        // ================= forward layer l = 2h : L1 -> L2 -> L3 =================
        {
            const int gb = (2 * h) * NQ;
            GATE(gb + 11, 0); GATE(gb + 10, 1); GATE(gb + 9, 2); GATE(gb + 8, 3);
            TRANSPOSE_A();                          // prior buf readers in-wave (or none)
            GATE(gb + 5, 0); GATE(gb + 4, 1); GATE(gb + 3, 2); GATE(gb + 2, 3);
            WFENCE();                               // prior T_a reads in-wave -> fence suffices
            TRANSPOSE_B();
            GATE(gb + 7, 0); GATE(gb + 6, 1); GATE(gb + 1, 2); GATE(gb + 0, 3);
            // CZ in L3: i=(j3,j2,lam5,lam4,w1,w0,j1,j0,lam3..0)   [R8-verified]
            {
                const int l5 = (lam >> 5) & 1, l4 = (lam >> 4) & 1, l3 = (lam >> 3) & 1;
                const int par = (l5 & l4) + (l4 & w1) + (w1 & w0) + __popc(lam & (lam >> 1) & 0x7);
                const float base = (par & 1) ? -1.0f : 1.0f;
                const float fA = l5 ? -1.0f : 1.0f;
                const float fB = w0 ? -1.0f : 1.0f;
                const float fC = l3 ? -1.0f : 1.0f;
#pragma unroll
                for (int j = 0; j < 16; ++j) {
                    float s = base;
                    if (j & 4) s *= fA;
                    if (j & 2) s *= fB;
                    if (j & 1) s *= fC;
                    if ((((j & 12) == 12) ? 1 : 0) ^ (((j & 3) == 3) ? 1 : 0)) s = -s; // compile-time
                    st[j] *= s;
                }
            }
        }
        // ================= reverse layer l = 2h+1 : L3 -> L2 -> L1 =================
        {
            const int gb = (2 * h + 1) * NQ;
            GATE(gb + 7, 0); GATE(gb + 6, 1); GATE(gb + 1, 2); GATE(gb + 0, 3);
            __syncthreads();                        // prior T_b reads cross-wave
            TRANSPOSE_B();                          // involution: same formula back
            GATE(gb + 5, 0); GATE(gb + 4, 1); GATE(gb + 3, 2); GATE(gb + 2, 3);
            __syncthreads();                        // prior T_b reads cross-wave
            TRANSPOSE_A();
            GATE(gb + 11, 0); GATE(gb + 10, 1); GATE(gb + 9, 2); GATE(gb + 8, 3);
            // CZ in L1 (R6-verified)
            {
                const int par = __popc(lam & (lam >> 1)) + ((lam & 1) & w1) + (w1 & w0);
                const float base = (par & 1) ? -1.0f : 1.0f;
                const float sHi = w0 ? -base : base;   // (7,8) = w0 & j3
#pragma unroll
                for (int j = 0; j < 16; ++j) {
                    float s = (j & 8) ? sHi : base;
                    if (__popc(j & (j >> 1)) & 1) s = -s;  // compile-time per j
                    st[j] *= s;
                }
            }
        }
    }

    // --- measurement in L1 ---
    float tot = 0.f, m8 = 0.f, m9 = 0.f, m10 = 0.f, m11 = 0.f;
#pragma unroll
    for (int j = 0; j < 16; ++j) {
        const float p = st[j].x * st[j].x + st[j].y * st[j].y;
        tot += p;
        m8  += (j & 8) ? -p : p;
        m9  += (j & 4) ? -p : p;
        m10 += (j & 2) ? -p : p;
        m11 += (j & 1) ? -p : p;
    }
    float part[NQ];
#pragma unroll
    for (int q = 0; q < 6; ++q)
        part[q] = ((lam >> (5 - q)) & 1) ? -tot : tot;
    part[6] = w1 ? -tot : tot;
    part[7] = w0 ? -tot : tot;
    part[8] = m8; part[9] = m9; part[10] = m10; part[11] = m11;

#pragma unroll
    for (int off = 32; off > 0; off >>= 1) {
#pragma unroll
        for (int q = 0; q < NQ; ++q)
            part[q] += __shfl_down(part[q], off, 64);
    }
    if (lam == 0) {
#pragma unroll
        for (int q = 0; q < NQ; ++q) red[w][q] = part[q];
    }
    __syncthreads();
    if (tix < NQ) qout[tix] = red[0][tix] + red[1][tix] + red[2][tix] + red[3][tix];
    __syncthreads();

    if (tix < NA) {
        float acc = fc_b[tix];
#pragma unroll
        for (int q = 0; q < NQ; ++q)
            acc += qout[q] * fc_w[tix * NQ + q];
        out[b * NA + tix] = acc;
    }
}

extern "C" void kernel_launch(void* const* d_in, const int* in_sizes, int n_in,
                              void* d_out, int out_size, void* d_ws, size_t ws_size,
                              hipStream_t stream) {
    const float* x   = (const float*)d_in[0];
    const float* wts = (const float*)d_in[1];
    const float* fcw = (const float*)d_in[2];
    const float* fcb = (const float*)d_in[3];
    float* rots = (float*)d_ws;   // 48*8 f32 = 1536 B
    rot_setup_kernel<<<1, 64, 0, stream>>>(wts, rots);
    qdqn_kernel<<<BATCH, NT, 0, stream>>>(x, rots, fcw, fcb, (float*)d_out);
}

// Round 10
// 147.964 us; speedup vs baseline: 1.4715x; 1.2758x over previous
//
#include <hip/hip_runtime.h>
#include <math.h>

#define NQ 12
#define NL 4
#define NA 6
#define BATCH 4096
#define NT 256
#define RSTR 17   // f32 row stride for transpose buffer

typedef float f2 __attribute__((ext_vector_type(2)));

// HW-verified (R3-R9) packed complex primitives; (re,im) in a VGPR pair.
// Modifier semantics (confirmed by R3-verified CMACI): op_sel[k]=half feeding LO result,
// op_sel_hi[k]=half feeding HI result, neg_lo/neg_hi negate per operand per result half.
#define CMUL(d, u, a)  asm("v_pk_mul_f32 %0, %1, %2 op_sel_hi:[0,1]"                 : "=v"(d) : "v"(u), "v"(a))
#define CMACR(d, u, a) asm("v_pk_fma_f32 %0, %1, %2, %0 op_sel_hi:[0,1,1]"           : "+v"(d) : "v"(u), "v"(a))
#define CMACI(d, u, a) asm("v_pk_fma_f32 %0, %1, %2, %0 op_sel:[1,1,0] op_sel_hi:[1,0,1] neg_lo:[1,0,0]" : "+v"(d) : "v"(u), "v"(a))
// R10 scalar-broadcast variants (coefficient f2 = (c,s)):
//   RYMULS : d = (s*a.x, s*a.y)
//   RYMACNS: d += (-s*a.x, -s*a.y)
#define RYMULS(d, u, a)  asm("v_pk_mul_f32 %0, %1, %2 op_sel:[1,0] op_sel_hi:[1,1]"  : "=v"(d) : "v"(u), "v"(a))
#define RYMACNS(d, u, a) asm("v_pk_fma_f32 %0, %1, %2, %0 op_sel:[1,0,0] op_sel_hi:[1,1,1] neg_lo:[1,0,0] neg_hi:[1,0,0]" : "+v"(d) : "v"(u), "v"(a))
#define WFENCE() asm volatile("s_waitcnt lgkmcnt(0)" ::: "memory")

// Real RY butterfly: n0 = c*a0 - s*a1 ; n1 = s*a0 + c*a1   (4 pk ops vs 8 for full Rot)
#define RYBFLY(A0, A1, CS) do { \
    f2 _a0 = (A0), _a1 = (A1), _n0, _n1; \
    CMUL  (_n0, CS, _a0); RYMACNS(_n0, CS, _a1); \
    RYMULS(_n1, CS, _a0); CMACR  (_n1, CS, _a1); \
    (A0) = _n0; (A1) = _n1; } while (0)

#define RYGATE(gidx, bq) do { \
    const f2 cs = *(const f2*)(rots + (gidx) * 2); \
    const int S = 1 << (bq); \
    _Pragma("unroll") \
    for (int m = 0; m < 8; ++m) { \
        const int j0 = ((m & ~(S - 1)) << 1) | (m & (S - 1)); \
        RYBFLY(st[j0], st[j0 + S], cs); \
    } } while (0)

// Circuit algebra (R10): Rot(phi,theta,omega) = RZ(omega)*RY(theta)*RZ(phi)  [phi applied first].
// All RZ / CZ are diagonal -> fold: RZ(phi_0) into init; D_l = RZ(omega_l)*CZ*RZ(phi_{l+1})
// between RY layers (l=0,1,2); RZ(omega_3)+CZ_3 dropped (probs phase-invariant).
// alpha rows: r=0: phi_0/2 ; r=1..3: (omega_{r-1}+phi_r)/2. Diagonal phase per wire q:
// e^{+i a} if bit_q=1 else e^{-i a}. Factorized D = D_thread(8 wires) x D_reg[j](4 reg wires).
//
// Layouts (wire q <-> i-bit (11-q)): R8-verified, unchanged:
//  L1: i=(lam5..lam0,w1,w0,j3..j0)  L2: i=(lam5,lam4,j3..j0,w1,w0,lam3..0)
//  L3: i=(j3,j2,lam5,lam4,w1,w0,j1,j0,lam3..0)
// T_a / T_b transposes and CZ sign formulas: verbatim R8/R9 (verified).
//
// d_ws float layout: [0..95] 48 gates (c,s) | [96..143] alphas[4][12] | [144..271] dreg[4][16] (re,im)

__global__ void setup_kernel(const float* __restrict__ weights, float* __restrict__ ws) {
    const int t = threadIdx.x;   // 64 threads
    if (t < NL * NQ) {
        // gate (c,s) = (cos(theta/2), sin(theta/2))
        const float th = weights[t * 3 + 1];
        float s, c;
        sincosf(0.5f * th, &s, &c);
        ws[t * 2 + 0] = c; ws[t * 2 + 1] = s;
        // alphas row r = t/12, wire q = t%12
        const int r = t / NQ, q = t % NQ;
        float a;
        if (r == 0) a = 0.5f * weights[q * 3 + 0];                                   // phi_0/2
        else        a = 0.5f * (weights[((r - 1) * NQ + q) * 3 + 2] +                // omega_{r-1}
                                 weights[(r * NQ + q) * 3 + 0]);                     // + phi_r
        ws[96 + t] = a;
    }
    // dreg: d = t>>4 (row), j = t&15. Rows 0,2: L1 reg wires {8,9,10,11}; rows 1,3: L3 reg wires {0,1,6,7}.
    {
        const int d = t >> 4, j = t & 15;
        int wq[4];
        if (d == 1 || d == 3) { wq[0] = 0; wq[1] = 1; wq[2] = 6; wq[3] = 7; }
        else                  { wq[0] = 8; wq[1] = 9; wq[2] = 10; wq[3] = 11; }
        float g = 0.0f;
#pragma unroll
        for (int k = 0; k < 4; ++k) {
            const int q = wq[k];
            const float a = (d == 0) ? 0.5f * weights[q * 3 + 0]
                                     : 0.5f * (weights[((d - 1) * NQ + q) * 3 + 2] +
                                               weights[(d * NQ + q) * 3 + 0]);
            g += ((j >> (3 - k)) & 1) ? a : -a;
        }
        float sg, cg;
        sincosf(g, &sg, &cg);
        ws[144 + (d * 16 + j) * 2 + 0] = cg;
        ws[144 + (d * 16 + j) * 2 + 1] = sg;
    }
}

// st[j] *= (cos b, sin b) * dreg_tab[j]
__device__ __forceinline__ void apply_phase(f2* st, const float* tab, float beta) {
    float sb, cb;
    sincosf(beta, &sb, &cb);
    const f2 Dth = (f2){cb, sb};
#pragma unroll
    for (int j = 0; j < 16; ++j) {
        const f2 a = st[j];
        f2 t, u;
        CMUL(t, Dth, a); CMACI(t, Dth, a);
        const f2 dg = *(const f2*)(tab + 2 * j);
        CMUL(u, dg, t); CMACI(u, dg, t);
        st[j] = u;
    }
}

__global__ __launch_bounds__(NT) void qdqn_kernel(
    const float* __restrict__ x,       // [BATCH,12]
    const float* __restrict__ rots,    // d_ws tables
    const float* __restrict__ fc_w,    // [6,12]
    const float* __restrict__ fc_b,    // [6]
    float* __restrict__ out)           // [BATCH,6]
{
    __shared__ __align__(16) float buf[NT * RSTR];   // 17408 B transpose buffer
    __shared__ float encc[NQ], encs[NQ];
    __shared__ float red[4][NQ];
    __shared__ float qout[NQ];

    const int tix = threadIdx.x;
    const int lam = tix & 63;
    const int w   = tix >> 6;
    const int w1  = (w >> 1) & 1, w0 = w & 1;
    const int b   = blockIdx.x;

    const float* alph = rots + 96;    // [4][12]
    const float* dreg = rots + 144;   // [4][16] f2

    if (tix < NQ) {
        float s, c;
        sincosf(0.5f * x[b * NQ + tix], &s, &c);
        encc[tix] = c; encs[tix] = s;
    }
    __syncthreads();

    // --- RY product state in L1 (real) ---
    f2 st[16];
    {
        float pre = 1.0f;
#pragma unroll
        for (int q = 0; q < 6; ++q)
            pre *= ((lam >> (5 - q)) & 1) ? encs[q] : encc[q];
        pre *= w1 ? encs[6] : encc[6];
        pre *= w0 ? encs[7] : encc[7];
        const float c8 = encc[8],  s8 = encs[8];
        const float c9 = encc[9],  s9 = encs[9];
        const float cA = encc[10], sA = encs[10];
        const float cB = encc[11], sB = encs[11];
#pragma unroll
        for (int j = 0; j < 16; ++j) {
            float v = pre;
            v *= (j & 8) ? s8 : c8;
            v *= (j & 4) ? s9 : c9;
            v *= (j & 2) ? sA : cA;
            v *= (j & 1) ? sB : cB;
            st[j] = (f2){ v, 0.0f };
        }
    }

    // beta over L1 thread wires {0..7}: bits lam5..lam0, w1, w0
#define BETA_L1(al) ( (((lam >> 5) & 1) ? (al)[0] : -(al)[0]) + (((lam >> 4) & 1) ? (al)[1] : -(al)[1]) \
                    + (((lam >> 3) & 1) ? (al)[2] : -(al)[2]) + (((lam >> 2) & 1) ? (al)[3] : -(al)[3]) \
                    + (((lam >> 1) & 1) ? (al)[4] : -(al)[4]) + (((lam >> 0) & 1) ? (al)[5] : -(al)[5]) \
                    + (w1 ? (al)[6] : -(al)[6]) + (w0 ? (al)[7] : -(al)[7]) )
    // beta over L3 thread wires {2,3,4,5,8,9,10,11}: bits lam5,lam4,w1,w0,lam3,lam2,lam1,lam0
#define BETA_L3(al) ( (((lam >> 5) & 1) ? (al)[2] : -(al)[2]) + (((lam >> 4) & 1) ? (al)[3] : -(al)[3]) \
                    + (w1 ? (al)[4] : -(al)[4]) + (w0 ? (al)[5] : -(al)[5]) \
                    + (((lam >> 3) & 1) ? (al)[8] : -(al)[8]) + (((lam >> 2) & 1) ? (al)[9] : -(al)[9]) \
                    + (((lam >> 1) & 1) ? (al)[10] : -(al)[10]) + (((lam >> 0) & 1) ? (al)[11] : -(al)[11]) )

    // --- init diagonal: RZ(phi_0) in L1 (row 0) ---
    apply_phase(st, dreg + 0 * 32, BETA_L1(alph + 0 * NQ));

    const int col_b = ((lam >> 4) << 2) | w;
    const int row_a = (w << 6) | (lam & 0x30);
    const int col_a = lam & 0xF;

#define TRANSPOSE_A() do { \
    WFENCE(); \
    _Pragma("unroll") for (int j = 0; j < 16; ++j) buf[tix * RSTR + j] = st[j].x; \
    WFENCE(); \
    _Pragma("unroll") for (int j = 0; j < 16; ++j) st[j].x = buf[(row_a | j) * RSTR + col_a]; \
    WFENCE(); \
    _Pragma("unroll") for (int j = 0; j < 16; ++j) buf[tix * RSTR + j] = st[j].y; \
    WFENCE(); \
    _Pragma("unroll") for (int j = 0; j < 16; ++j) st[j].y = buf[(row_a | j) * RSTR + col_a]; \
    } while (0)

#define TRANSPOSE_B() do { \
    _Pragma("unroll") for (int j = 0; j < 16; ++j) buf[tix * RSTR + j] = st[j].x; \
    __syncthreads(); \
    _Pragma("unroll") for (int j = 0; j < 16; ++j) \
        st[j].x = buf[(((j & 3) << 6) | ((j >> 2) << 4) | (lam & 0xF)) * RSTR + col_b]; \
    __syncthreads(); \
    _Pragma("unroll") for (int j = 0; j < 16; ++j) buf[tix * RSTR + j] = st[j].y; \
    __syncthreads(); \
    _Pragma("unroll") for (int j = 0; j < 16; ++j) \
        st[j].y = buf[(((j & 3) << 6) | ((j >> 2) << 4) | (lam & 0xF)) * RSTR + col_b]; \
    } while (0)

#pragma unroll 1
    for (int h = 0; h < 2; ++h) {
        // ============ forward layer l = 2h : L1 -> L2 -> L3 ============
        {
            const int gb = (2 * h) * NQ;
            RYGATE(gb + 11, 0); RYGATE(gb + 10, 1); RYGATE(gb + 9, 2); RYGATE(gb + 8, 3);
            TRANSPOSE_A();
            RYGATE(gb + 5, 0); RYGATE(gb + 4, 1); RYGATE(gb + 3, 2); RYGATE(gb + 2, 3);
            WFENCE();
            TRANSPOSE_B();
            RYGATE(gb + 7, 0); RYGATE(gb + 6, 1); RYGATE(gb + 1, 2); RYGATE(gb + 0, 3);
            // CZ sign in L3 (R8-verified, verbatim)
            {
                const int l5 = (lam >> 5) & 1, l4 = (lam >> 4) & 1, l3 = (lam >> 3) & 1;
                const int par = (l5 & l4) + (l4 & w1) + (w1 & w0) + __popc(lam & (lam >> 1) & 0x7);
                const float base = (par & 1) ? -1.0f : 1.0f;
                const float fA = l5 ? -1.0f : 1.0f;
                const float fB = w0 ? -1.0f : 1.0f;
                const float fC = l3 ? -1.0f : 1.0f;
#pragma unroll
                for (int j = 0; j < 16; ++j) {
                    float s = base;
                    if (j & 4) s *= fA;
                    if (j & 2) s *= fB;
                    if (j & 1) s *= fC;
                    if ((((j & 12) == 12) ? 1 : 0) ^ (((j & 3) == 3) ? 1 : 0)) s = -s;
                    st[j] *= s;
                }
            }
            // fused RZ diagonal, row 2h+1, in L3
            {
                const int row = 2 * h + 1;
                apply_phase(st, dreg + row * 32, BETA_L3(alph + row * NQ));
            }
        }
        // ============ reverse layer l = 2h+1 : L3 -> L2 -> L1 ============
        {
            const int gb = (2 * h + 1) * NQ;
            RYGATE(gb + 7, 0); RYGATE(gb + 6, 1); RYGATE(gb + 1, 2); RYGATE(gb + 0, 3);
            __syncthreads();
            TRANSPOSE_B();
            RYGATE(gb + 5, 0); RYGATE(gb + 4, 1); RYGATE(gb + 3, 2); RYGATE(gb + 2, 3);
            __syncthreads();
            TRANSPOSE_A();
            RYGATE(gb + 11, 0); RYGATE(gb + 10, 1); RYGATE(gb + 9, 2); RYGATE(gb + 8, 3);
            if (h == 0) {
                // CZ sign in L1 (R6/R8-verified, verbatim)
                {
                    const int par = __popc(lam & (lam >> 1)) + ((lam & 1) & w1) + (w1 & w0);
                    const float base = (par & 1) ? -1.0f : 1.0f;
                    const float sHi = w0 ? -base : base;
#pragma unroll
                    for (int j = 0; j < 16; ++j) {
                        float s = (j & 8) ? sHi : base;
                        if (__popc(j & (j >> 1)) & 1) s = -s;
                        st[j] *= s;
                    }
                }
                // fused RZ diagonal, row 2, in L1
                apply_phase(st, dreg + 2 * 32, BETA_L1(alph + 2 * NQ));
            }
            // h==1 (layer 3): trailing RZ(omega_3)+CZ dropped — diagonals don't affect probs
        }
    }

    // --- measurement in L1 ---
    float tot = 0.f, m8 = 0.f, m9 = 0.f, m10 = 0.f, m11 = 0.f;
#pragma unroll
    for (int j = 0; j < 16; ++j) {
        const float p = st[j].x * st[j].x + st[j].y * st[j].y;
        tot += p;
        m8  += (j & 8) ? -p : p;
        m9  += (j & 4) ? -p : p;
        m10 += (j & 2) ? -p : p;
        m11 += (j & 1) ? -p : p;
    }
    float part[NQ];
#pragma unroll
    for (int q = 0; q < 6; ++q)
        part[q] = ((lam >> (5 - q)) & 1) ? -tot : tot;
    part[6] = w1 ? -tot : tot;
    part[7] = w0 ? -tot : tot;
    part[8] = m8; part[9] = m9; part[10] = m10; part[11] = m11;

#pragma unroll
    for (int off = 32; off > 0; off >>= 1) {
#pragma unroll
        for (int q = 0; q < NQ; ++q)
            part[q] += __shfl_down(part[q], off, 64);
    }
    if (lam == 0) {
#pragma unroll
        for (int q = 0; q < NQ; ++q) red[w][q] = part[q];
    }
    __syncthreads();
    if (tix < NQ) qout[tix] = red[0][tix] + red[1][tix] + red[2][tix] + red[3][tix];
    __syncthreads();

    if (tix < NA) {
        float acc = fc_b[tix];
#pragma unroll
        for (int q = 0; q < NQ; ++q)
            acc += qout[q] * fc_w[tix * NQ + q];
        out[b * NA + tix] = acc;
    }
}

extern "C" void kernel_launch(void* const* d_in, const int* in_sizes, int n_in,
                              void* d_out, int out_size, void* d_ws, size_t ws_size,
                              hipStream_t stream) {
    const float* x   = (const float*)d_in[0];
    const float* wts = (const float*)d_in[1];
    const float* fcw = (const float*)d_in[2];
    const float* fcb = (const float*)d_in[3];
    float* tabs = (float*)d_ws;   // 272 f32 = 1088 B
    setup_kernel<<<1, 64, 0, stream>>>(wts, tabs);
    qdqn_kernel<<<BATCH, NT, 0, stream>>>(x, tabs, fcw, fcb, (float*)d_out);
}

// Round 11
// 146.782 us; speedup vs baseline: 1.4833x; 1.0080x over previous
//
#include <hip/hip_runtime.h>
#include <math.h>

#define NQ 12
#define NL 4
#define NA 6
#define BATCH 4096
#define NT 256
#define RSTR 17   // buf row stride in f2 units (R8-verified b64 transpose; conflicts at 4-dword/bank floor)

typedef float f2 __attribute__((ext_vector_type(2)));

// HW-verified (R3-R10) packed complex primitives; (re,im) in a VGPR pair.
#define CMUL(d, u, a)  asm("v_pk_mul_f32 %0, %1, %2 op_sel_hi:[0,1]"                 : "=v"(d) : "v"(u), "v"(a))
#define CMACR(d, u, a) asm("v_pk_fma_f32 %0, %1, %2, %0 op_sel_hi:[0,1,1]"           : "+v"(d) : "v"(u), "v"(a))
#define CMACI(d, u, a) asm("v_pk_fma_f32 %0, %1, %2, %0 op_sel:[1,1,0] op_sel_hi:[1,0,1] neg_lo:[1,0,0]" : "+v"(d) : "v"(u), "v"(a))
// R10-verified scalar-broadcast variants (coefficient f2 = (c,s)):
#define RYMULS(d, u, a)  asm("v_pk_mul_f32 %0, %1, %2 op_sel:[1,0] op_sel_hi:[1,1]"  : "=v"(d) : "v"(u), "v"(a))
#define RYMACNS(d, u, a) asm("v_pk_fma_f32 %0, %1, %2, %0 op_sel:[1,0,0] op_sel_hi:[1,1,1] neg_lo:[1,0,0] neg_hi:[1,0,0]" : "+v"(d) : "v"(u), "v"(a))
#define WFENCE() asm volatile("s_waitcnt lgkmcnt(0)" ::: "memory")

// Real RY butterfly: n0 = c*a0 - s*a1 ; n1 = s*a0 + c*a1   (4 pk ops)
#define RYBFLY(A0, A1, CS) do { \
    f2 _a0 = (A0), _a1 = (A1), _n0, _n1; \
    CMUL  (_n0, CS, _a0); RYMACNS(_n0, CS, _a1); \
    RYMULS(_n1, CS, _a0); CMACR  (_n1, CS, _a1); \
    (A0) = _n0; (A1) = _n1; } while (0)

#define RYGATE(gidx, bq) do { \
    const f2 cs = *(const f2*)(rots + (gidx) * 2); \
    const int S = 1 << (bq); \
    _Pragma("unroll") \
    for (int m = 0; m < 8; ++m) { \
        const int j0 = ((m & ~(S - 1)) << 1) | (m & (S - 1)); \
        RYBFLY(st[j0], st[j0 + S], cs); \
    } } while (0)

// Circuit algebra (R10-verified): Rot = RZ(omega)*RY(theta)*RZ(phi); diagonals folded:
// RZ(phi_0) into init; D_l = RZ(omega_l)*CZ*RZ(phi_{l+1}) between RY layers; trailing
// RZ(omega_3)+CZ_3 dropped (probs phase-invariant).
// Layouts (R8-verified): L1: i=(lam5..lam0,w1,w0,j3..j0); L2: i=(lam5,lam4,j3..j0,w1,w0,lam3..0);
// L3: i=(j3,j2,lam5,lam4,w1,w0,j1,j0,lam3..0).
// T_a (L1<->L2, involution, wave-local) / T_b (L2<->L3, involution, cross-wave): R8 formulas, f2/b64.
// d_ws float layout: [0..95] 48 gates (c,s) | [96..143] alphas[4][12] | [144..271] dreg[4][16] (re,im)

__global__ void setup_kernel(const float* __restrict__ weights, float* __restrict__ ws) {
    const int t = threadIdx.x;   // 64 threads
    if (t < NL * NQ) {
        const float th = weights[t * 3 + 1];
        float s, c;
        sincosf(0.5f * th, &s, &c);
        ws[t * 2 + 0] = c; ws[t * 2 + 1] = s;
        const int r = t / NQ, q = t % NQ;
        float a;
        if (r == 0) a = 0.5f * weights[q * 3 + 0];
        else        a = 0.5f * (weights[((r - 1) * NQ + q) * 3 + 2] +
                                 weights[(r * NQ + q) * 3 + 0]);
        ws[96 + t] = a;
    }
    {
        const int d = t >> 4, j = t & 15;
        int wq[4];
        if (d == 1 || d == 3) { wq[0] = 0; wq[1] = 1; wq[2] = 6; wq[3] = 7; }
        else                  { wq[0] = 8; wq[1] = 9; wq[2] = 10; wq[3] = 11; }
        float g = 0.0f;
#pragma unroll
        for (int k = 0; k < 4; ++k) {
            const int q = wq[k];
            const float a = (d == 0) ? 0.5f * weights[q * 3 + 0]
                                     : 0.5f * (weights[((d - 1) * NQ + q) * 3 + 2] +
                                               weights[(d * NQ + q) * 3 + 0]);
            g += ((j >> (3 - k)) & 1) ? a : -a;
        }
        float sg, cg;
        sincosf(g, &sg, &cg);
        ws[144 + (d * 16 + j) * 2 + 0] = cg;
        ws[144 + (d * 16 + j) * 2 + 1] = sg;
    }
}

// st[j] *= (cos b, sin b) * dreg_tab[j]   (R10-verified)
__device__ __forceinline__ void apply_phase(f2* st, const float* tab, float beta) {
    float sb, cb;
    sincosf(beta, &sb, &cb);
    const f2 Dth = (f2){cb, sb};
#pragma unroll
    for (int j = 0; j < 16; ++j) {
        const f2 a = st[j];
        f2 t, u;
        CMUL(t, Dth, a); CMACI(t, Dth, a);
        const f2 dg = *(const f2*)(tab + 2 * j);
        CMUL(u, dg, t); CMACI(u, dg, t);
        st[j] = u;
    }
}

__global__ __launch_bounds__(NT) void qdqn_kernel(
    const float* __restrict__ x,       // [BATCH,12]
    const float* __restrict__ rots,    // d_ws tables
    const float* __restrict__ fc_w,    // [6,12]
    const float* __restrict__ fc_b,    // [6]
    float* __restrict__ out)           // [BATCH,6]
{
    __shared__ __align__(16) f2 buf[NT * RSTR];   // 34816 B f2 transpose buffer (R8-verified b64 path)
    __shared__ float encc[NQ], encs[NQ];
    __shared__ float red[4][NQ];
    __shared__ float qout[NQ];

    const int tix = threadIdx.x;
    const int lam = tix & 63;
    const int w   = tix >> 6;
    const int w1  = (w >> 1) & 1, w0 = w & 1;
    const int b   = blockIdx.x;

    const float* alph = rots + 96;
    const float* dreg = rots + 144;

    if (tix < NQ) {
        float s, c;
        sincosf(0.5f * x[b * NQ + tix], &s, &c);
        encc[tix] = c; encs[tix] = s;
    }
    __syncthreads();

    // --- RY product state in L1 (real) ---
    f2 st[16];
    {
        float pre = 1.0f;
#pragma unroll
        for (int q = 0; q < 6; ++q)
            pre *= ((lam >> (5 - q)) & 1) ? encs[q] : encc[q];
        pre *= w1 ? encs[6] : encc[6];
        pre *= w0 ? encs[7] : encc[7];
        const float c8 = encc[8],  s8 = encs[8];
        const float c9 = encc[9],  s9 = encs[9];
        const float cA = encc[10], sA = encs[10];
        const float cB = encc[11], sB = encs[11];
#pragma unroll
        for (int j = 0; j < 16; ++j) {
            float v = pre;
            v *= (j & 8) ? s8 : c8;
            v *= (j & 4) ? s9 : c9;
            v *= (j & 2) ? sA : cA;
            v *= (j & 1) ? sB : cB;
            st[j] = (f2){ v, 0.0f };
        }
    }

#define BETA_L1(al) ( (((lam >> 5) & 1) ? (al)[0] : -(al)[0]) + (((lam >> 4) & 1) ? (al)[1] : -(al)[1]) \
                    + (((lam >> 3) & 1) ? (al)[2] : -(al)[2]) + (((lam >> 2) & 1) ? (al)[3] : -(al)[3]) \
                    + (((lam >> 1) & 1) ? (al)[4] : -(al)[4]) + (((lam >> 0) & 1) ? (al)[5] : -(al)[5]) \
                    + (w1 ? (al)[6] : -(al)[6]) + (w0 ? (al)[7] : -(al)[7]) )
#define BETA_L3(al) ( (((lam >> 5) & 1) ? (al)[2] : -(al)[2]) + (((lam >> 4) & 1) ? (al)[3] : -(al)[3]) \
                    + (w1 ? (al)[4] : -(al)[4]) + (w0 ? (al)[5] : -(al)[5]) \
                    + (((lam >> 3) & 1) ? (al)[8] : -(al)[8]) + (((lam >> 2) & 1) ? (al)[9] : -(al)[9]) \
                    + (((lam >> 1) & 1) ? (al)[10] : -(al)[10]) + (((lam >> 0) & 1) ? (al)[11] : -(al)[11]) )

    // --- init diagonal: RZ(phi_0) in L1 ---
    apply_phase(st, dreg + 0 * 32, BETA_L1(alph + 0 * NQ));

    const int col_b = ((lam >> 4) << 2) | w;
    const int row_a = (w << 6) | (lam & 0x30);
    const int col_a = lam & 0xF;

    // f2/b64 transposes (R8-verified formulas + barrier placement)
#define TRANSPOSE_A_FWD() do { \
    WFENCE(); \
    _Pragma("unroll") for (int j = 0; j < 16; ++j) buf[tix * RSTR + j] = st[j]; \
    WFENCE(); \
    _Pragma("unroll") for (int j = 0; j < 16; ++j) st[j] = buf[(row_a | j) * RSTR + col_a]; \
    } while (0)

#define TB_READ(j) buf[(((j & 3) << 6) | ((j >> 2) << 4) | (lam & 0xF)) * RSTR + col_b]

#pragma unroll 1
    for (int h = 0; h < 2; ++h) {
        // ============ forward layer l = 2h : L1 -> L2 -> L3 ============
        {
            const int gb = (2 * h) * NQ;
            RYGATE(gb + 11, 0); RYGATE(gb + 10, 1); RYGATE(gb + 9, 2); RYGATE(gb + 8, 3);
            TRANSPOSE_A_FWD();                      // wave-local (prior readers in-wave or none)
            RYGATE(gb + 5, 0); RYGATE(gb + 4, 1); RYGATE(gb + 3, 2); RYGATE(gb + 2, 3);
            // T_b (cross-wave reads)
            WFENCE();
#pragma unroll
            for (int j = 0; j < 16; ++j) buf[tix * RSTR + j] = st[j];
            __syncthreads();
#pragma unroll
            for (int j = 0; j < 16; ++j) st[j] = TB_READ(j);
            RYGATE(gb + 7, 0); RYGATE(gb + 6, 1); RYGATE(gb + 1, 2); RYGATE(gb + 0, 3);
            // CZ sign in L3 (R8-verified)
            {
                const int l5 = (lam >> 5) & 1, l4 = (lam >> 4) & 1, l3 = (lam >> 3) & 1;
                const int par = (l5 & l4) + (l4 & w1) + (w1 & w0) + __popc(lam & (lam >> 1) & 0x7);
                const float base = (par & 1) ? -1.0f : 1.0f;
                const float fA = l5 ? -1.0f : 1.0f;
                const float fB = w0 ? -1.0f : 1.0f;
                const float fC = l3 ? -1.0f : 1.0f;
#pragma unroll
                for (int j = 0; j < 16; ++j) {
                    float s = base;
                    if (j & 4) s *= fA;
                    if (j & 2) s *= fB;
                    if (j & 1) s *= fC;
                    if ((((j & 12) == 12) ? 1 : 0) ^ (((j & 3) == 3) ? 1 : 0)) s = -s;
                    st[j] *= s;
                }
            }
            // fused RZ diagonal, row 2h+1, in L3
            apply_phase(st, dreg + (2 * h + 1) * 32, BETA_L3(alph + (2 * h + 1) * NQ));
        }
        // ============ reverse layer l = 2h+1 : L3 -> L2 -> L1 ============
        {
            const int gb = (2 * h + 1) * NQ;
            RYGATE(gb + 7, 0); RYGATE(gb + 6, 1); RYGATE(gb + 1, 2); RYGATE(gb + 0, 3);
            // T_b back (involution; prior T_b reads cross-wave -> barrier before writes)
            __syncthreads();
#pragma unroll
            for (int j = 0; j < 16; ++j) buf[tix * RSTR + j] = st[j];
            __syncthreads();
#pragma unroll
            for (int j = 0; j < 16; ++j) st[j] = TB_READ(j);
            RYGATE(gb + 5, 0); RYGATE(gb + 4, 1); RYGATE(gb + 3, 2); RYGATE(gb + 2, 3);
            // T_a back (prior T_b reads cross-wave -> barrier before writes; reads wave-local)
            __syncthreads();
#pragma unroll
            for (int j = 0; j < 16; ++j) buf[tix * RSTR + j] = st[j];
            WFENCE();
#pragma unroll
            for (int j = 0; j < 16; ++j) st[j] = buf[(row_a | j) * RSTR + col_a];
            RYGATE(gb + 11, 0); RYGATE(gb + 10, 1); RYGATE(gb + 9, 2); RYGATE(gb + 8, 3);
            if (h == 0) {
                // CZ sign in L1 (R6/R8-verified)
                {
                    const int par = __popc(lam & (lam >> 1)) + ((lam & 1) & w1) + (w1 & w0);
                    const float base = (par & 1) ? -1.0f : 1.0f;
                    const float sHi = w0 ? -base : base;
#pragma unroll
                    for (int j = 0; j < 16; ++j) {
                        float s = (j & 8) ? sHi : base;
                        if (__popc(j & (j >> 1)) & 1) s = -s;
                        st[j] *= s;
                    }
                }
                // fused RZ diagonal, row 2, in L1
                apply_phase(st, dreg + 2 * 32, BETA_L1(alph + 2 * NQ));
            }
            // h==1: trailing diagonals dropped (probs phase-invariant)
        }
    }

    // --- measurement in L1 ---
    float tot = 0.f, m8 = 0.f, m9 = 0.f, m10 = 0.f, m11 = 0.f;
#pragma unroll
    for (int j = 0; j < 16; ++j) {
        const float p = st[j].x * st[j].x + st[j].y * st[j].y;
        tot += p;
        m8  += (j & 8) ? -p : p;
        m9  += (j & 4) ? -p : p;
        m10 += (j & 2) ? -p : p;
        m11 += (j & 1) ? -p : p;
    }
    float part[NQ];
#pragma unroll
    for (int q = 0; q < 6; ++q)
        part[q] = ((lam >> (5 - q)) & 1) ? -tot : tot;
    part[6] = w1 ? -tot : tot;
    part[7] = w0 ? -tot : tot;
    part[8] = m8; part[9] = m9; part[10] = m10; part[11] = m11;

#pragma unroll
    for (int off = 32; off > 0; off >>= 1) {
#pragma unroll
        for (int q = 0; q < NQ; ++q)
            part[q] += __shfl_down(part[q], off, 64);
    }
    if (lam == 0) {
#pragma unroll
        for (int q = 0; q < NQ; ++q) red[w][q] = part[q];
    }
    __syncthreads();
    if (tix < NQ) qout[tix] = red[0][tix] + red[1][tix] + red[2][tix] + red[3][tix];
    __syncthreads();

    if (tix < NA) {
        float acc = fc_b[tix];
#pragma unroll
        for (int q = 0; q < NQ; ++q)
            acc += qout[q] * fc_w[tix * NQ + q];
        out[b * NA + tix] = acc;
    }
}

extern "C" void kernel_launch(void* const* d_in, const int* in_sizes, int n_in,
                              void* d_out, int out_size, void* d_ws, size_t ws_size,
                              hipStream_t stream) {
    const float* x   = (const float*)d_in[0];
    const float* wts = (const float*)d_in[1];
    const float* fcw = (const float*)d_in[2];
    const float* fcb = (const float*)d_in[3];
    float* tabs = (float*)d_ws;   // 272 f32 = 1088 B
    setup_kernel<<<1, 64, 0, stream>>>(wts, tabs);
    qdqn_kernel<<<BATCH, NT, 0, stream>>>(x, tabs, fcw, fcb, (float*)d_out);
}